// Round 3
// baseline (98.198 us; speedup 1.0000x reference)
//
#include <hip/hip_runtime.h>
#include <hip/hip_bf16.h>

typedef __bf16 bf16x8 __attribute__((ext_vector_type(8)));
typedef __bf16 bf16x4 __attribute__((ext_vector_type(4)));
typedef float  f32x4  __attribute__((ext_vector_type(4)));

#define TQ   8192
#define DD   64
#define WW   128
#define PSTR 264   // padded row stride (bf16 elems) for Vt and P: 528B = 132 dwords == 4 (mod 32)

__global__ __launch_bounds__(512, 2)
void lattn_kernel(const float* __restrict__ q, const float* __restrict__ k,
                  const float* __restrict__ v, float* __restrict__ out)
{
    // LDS: K 32KB (swizzled), Vt 33KB (transposed, padded), P 66KB (per-wave) = 131KB
    __shared__ __bf16 Klds[256 * 64];
    __shared__ __bf16 Vt[64 * PSTR];
    __shared__ __bf16 Plds[8 * 16 * PSTR];

    const int bx   = blockIdx.x;
    const int bh   = bx >> 6;        // 0..31
    const int w    = bx & 63;        // window 0..63
    const int tid  = threadIdx.x;    // 0..511
    const int lane = tid & 63;
    const int wv   = tid >> 6;       // wave 0..7
    const int q15  = lane & 15;
    const int g    = lane >> 4;      // 0..3

    const size_t base = ((size_t)bh * TQ + (size_t)w * WW) * DD;   // q/out window base
    const int    krow0 = w * WW - WW;                              // first key row (may be <0 for w=0)
    const bool   w0    = (w == 0);

    // ---- Q fragments: global -> regs (bf16). A-frag: row=lane&15, k = g*8 + j' + 32*step ----
    const int qrow = wv * 16 + q15;
    const float* qp = q + base + (size_t)qrow * DD + g * 8;
    f32x4 q0a = *(const f32x4*)(qp);
    f32x4 q0b = *(const f32x4*)(qp + 4);
    f32x4 q1a = *(const f32x4*)(qp + 32);
    f32x4 q1b = *(const f32x4*)(qp + 36);
    bf16x8 qa0, qa1;
    #pragma unroll
    for (int e = 0; e < 4; ++e) {
        qa0[e]     = (__bf16)q0a[e];
        qa0[4 + e] = (__bf16)q0b[e];
        qa1[e]     = (__bf16)q1a[e];
        qa1[4 + e] = (__bf16)q1b[e];
    }

    // ---- Stage K: [256 keys][64 d] bf16, XOR-swizzled (elem ^= (j&7)<<3) ----
    #pragma unroll
    for (int it = 0; it < 8; ++it) {
        int flat4 = it * 512 + tid;          // 0..4095 float4-chunks
        int j  = flat4 >> 4;                 // key row 0..255
        int d0 = (flat4 & 15) * 4;           // d 0..60
        int gk = krow0 + j;
        f32x4 val = (f32x4){0.f, 0.f, 0.f, 0.f};
        if (gk >= 0) val = *(const f32x4*)(k + ((size_t)bh * TQ + gk) * DD + d0);
        bf16x4 b;
        #pragma unroll
        for (int e = 0; e < 4; ++e) b[e] = (__bf16)val[e];
        *(bf16x4*)&Klds[j * 64 + (d0 ^ ((j & 7) << 3))] = b;
    }

    // ---- Stage V transposed: Vt[d][j], row stride PSTR (padded) ----
    #pragma unroll
    for (int it = 0; it < 8; ++it) {
        int R  = it * 8 + wv;                // region 0..63
        int jb = R >> 2, db = R & 3;
        int j  = jb * 16 + q15;              // key row
        int d0 = db * 16 + g * 4;            // d chunk
        int gv = krow0 + j;
        f32x4 val = (f32x4){0.f, 0.f, 0.f, 0.f};
        if (gv >= 0) val = *(const f32x4*)(v + ((size_t)bh * TQ + gv) * DD + d0);
        #pragma unroll
        for (int c = 0; c < 4; ++c) Vt[(d0 + c) * PSTR + j] = (__bf16)val[c];
    }
    __syncthreads();

    // ---- S = Q K^T : 16 key-tiles x 2 k-steps. B-frag: col=lane&15 (key), k=d ----
    f32x4 accS[16];
    #pragma unroll
    for (int t = 0; t < 16; ++t) accS[t] = (f32x4){0.f, 0.f, 0.f, 0.f};
    #pragma unroll
    for (int t = 0; t < 16; ++t) {
        int j  = t * 16 + q15;
        int rb = j * 64;
        int sw = (j & 7) << 3;
        bf16x8 kb0 = *(const bf16x8*)&Klds[rb + ((g * 8) ^ sw)];
        bf16x8 kb1 = *(const bf16x8*)&Klds[rb + ((32 + g * 8) ^ sw)];
        accS[t] = __builtin_amdgcn_mfma_f32_16x16x32_bf16(qa0, kb0, accS[t], 0, 0, 0);
        accS[t] = __builtin_amdgcn_mfma_f32_16x16x32_bf16(qa1, kb1, accS[t], 0, 0, 0);
    }

    // ---- mask + softmax (C-layout: row = g*4+r, col j = t*16+q15) ----
    const float SCALE = 0.125f;   // D^-0.5
    float mx[4] = {-3.4e38f, -3.4e38f, -3.4e38f, -3.4e38f};
    #pragma unroll
    for (int t = 0; t < 16; ++t) {
        int j = t * 16 + q15;
        #pragma unroll
        for (int r = 0; r < 4; ++r) {
            int i = wv * 16 + g * 4 + r;          // local query row 0..127
            float sv = accS[t][r] * SCALE;
            if ((j > i + 128) || (w0 && j < 128)) sv = -3.0e38f;
            accS[t][r] = sv;
            mx[r] = fmaxf(mx[r], sv);
        }
    }
    #pragma unroll
    for (int mb = 1; mb < 16; mb <<= 1) {
        #pragma unroll
        for (int r = 0; r < 4; ++r) mx[r] = fmaxf(mx[r], __shfl_xor(mx[r], mb, 64));
    }
    float sm[4] = {0.f, 0.f, 0.f, 0.f};
    #pragma unroll
    for (int t = 0; t < 16; ++t) {
        #pragma unroll
        for (int r = 0; r < 4; ++r) {
            float p = __expf(accS[t][r] - mx[r]);
            accS[t][r] = p;
            sm[r] += p;
        }
    }
    #pragma unroll
    for (int mb = 1; mb < 16; mb <<= 1) {
        #pragma unroll
        for (int r = 0; r < 4; ++r) sm[r] += __shfl_xor(sm[r], mb, 64);
    }
    float rs[4];
    #pragma unroll
    for (int r = 0; r < 4; ++r) rs[r] = 1.0f / sm[r];

    // ---- P -> per-wave LDS (bf16, unnormalized) ----
    __bf16* Pw = &Plds[wv * 16 * PSTR];
    #pragma unroll
    for (int r = 0; r < 4; ++r) {
        int lr = g * 4 + r;
        #pragma unroll
        for (int t = 0; t < 16; ++t) {
            Pw[lr * PSTR + t * 16 + q15] = (__bf16)accS[t][r];
        }
    }
    // Cross-lane LDS handoff (write rows g*4+r, read row q15) REQUIRES a
    // synchronization point: without it the compiler may hoist the ds_read
    // above the ds_writes (per-thread addresses look independent) -> race
    // seen in round 2 (first call passed, graph replays diverged, absmax 1.03).
    __syncthreads();

    // ---- O = P V : A-frag P (row=lane&15), B-frag Vt (col d=lane&15), k=j ----
    f32x4 accO[4];
    #pragma unroll
    for (int dt = 0; dt < 4; ++dt) accO[dt] = (f32x4){0.f, 0.f, 0.f, 0.f};
    const __bf16* Pr = &Plds[(wv * 16 + q15) * PSTR];
    #pragma unroll
    for (int s = 0; s < 8; ++s) {
        bf16x8 pa = *(const bf16x8*)&Pr[s * 32 + g * 8];
        #pragma unroll
        for (int dt = 0; dt < 4; ++dt) {
            bf16x8 vb = *(const bf16x8*)&Vt[(dt * 16 + q15) * PSTR + s * 32 + g * 8];
            accO[dt] = __builtin_amdgcn_mfma_f32_16x16x32_bf16(pa, vb, accO[dt], 0, 0, 0);
        }
    }

    // ---- write O (fp32), normalize by 1/rowsum ----
    float* op = out + base;
    #pragma unroll
    for (int dt = 0; dt < 4; ++dt) {
        #pragma unroll
        for (int r = 0; r < 4; ++r) {
            int i = wv * 16 + g * 4 + r;
            op[(size_t)i * DD + dt * 16 + q15] = accO[dt][r] * rs[r];
        }
    }
}

extern "C" void kernel_launch(void* const* d_in, const int* in_sizes, int n_in,
                              void* d_out, int out_size, void* d_ws, size_t ws_size,
                              hipStream_t stream) {
    const float* q = (const float*)d_in[0];
    const float* k = (const float*)d_in[1];
    const float* v = (const float*)d_in[2];
    float* out = (float*)d_out;
    dim3 grid(32 * 64);   // (B*H) * windows
    dim3 block(512);
    lattn_kernel<<<grid, block, 0, stream>>>(q, k, v, out);
}

// Round 4
// 90.013 us; speedup vs baseline: 1.0909x; 1.0909x over previous
//
#include <hip/hip_runtime.h>
#include <hip/hip_bf16.h>

typedef __bf16 bf16x8 __attribute__((ext_vector_type(8)));
typedef float  f32x4  __attribute__((ext_vector_type(4)));
typedef float  f32x16 __attribute__((ext_vector_type(16)));
typedef unsigned int u32x4 __attribute__((ext_vector_type(4)));

#define TQ 8192
#define DD 64
#define PSTRV 264   // Vt row stride in bf16 elems (132 dwords == 4 mod 32 -> spread banks)

static __device__ __forceinline__ unsigned pack2_bf16(float lo, float hi) {
    unsigned short a = __builtin_bit_cast(unsigned short, (__bf16)lo);
    unsigned short b = __builtin_bit_cast(unsigned short, (__bf16)hi);
    return ((unsigned)b << 16) | (unsigned)a;
}

__global__ __launch_bounds__(256, 4)
void lattn_kernel(const float* __restrict__ q, const float* __restrict__ k,
                  const float* __restrict__ v, float* __restrict__ out)
{
    // Single LDS buffer: V^T bf16 [64][PSTRV] during the flash loop,
    // reused as f32 [64][132] for the O^T -> coalesced-store transpose.
    __shared__ __align__(16) unsigned char smem[DD * PSTRV * 2];   // 33792 B -> 4 blocks/CU
    __bf16* Vt = (__bf16*)smem;
    float*  Ot = (float*)smem;

    const int bx   = blockIdx.x;
    const int bh   = bx >> 6;        // 0..31
    const int w    = bx & 63;        // window 0..63
    const int tid  = threadIdx.x;    // 0..255
    const int lane = tid & 63;
    const int wv   = tid >> 6;       // wave 0..3, handles queries wv*32..wv*32+31
    const int l31  = lane & 31;
    const int hi   = lane >> 5;

    const size_t base  = ((size_t)bh * TQ + w * 128) * DD;
    const int    krow0 = w * 128 - 128;          // first key row of the 256-key span

    // ---- Q B-frags (col = query i = wv*32+l31, k-slot d = hi*8 + 16s + e) ----
    bf16x8 qf[4];
    {
        const float* qp = q + base + (size_t)(wv * 32 + l31) * DD + hi * 8;
        #pragma unroll
        for (int s = 0; s < 4; ++s) {
            f32x4 a = *(const f32x4*)(qp + 16 * s);
            f32x4 b = *(const f32x4*)(qp + 16 * s + 4);
            #pragma unroll
            for (int e = 0; e < 4; ++e) { qf[s][e] = (__bf16)a[e]; qf[s][4 + e] = (__bf16)b[e]; }
        }
    }

    // ---- stage V^T: Vt[d][j], zero-fill j with negative global row (w==0) ----
    #pragma unroll
    for (int it = 0; it < 16; ++it) {
        int flat = it * 256 + tid;               // 0..4095 f32x4 chunks
        int j  = flat >> 4;                      // key 0..255
        int d0 = (flat & 15) * 4;
        int gr = krow0 + j;
        f32x4 val = {0.f, 0.f, 0.f, 0.f};
        if (gr >= 0) val = *(const f32x4*)(v + ((size_t)bh * TQ + gr) * DD + d0);
        #pragma unroll
        for (int c = 0; c < 4; ++c) Vt[(d0 + c) * PSTRV + j] = (__bf16)val[c];
    }
    __syncthreads();

    // ---- flash loop over 32-key tiles (causal: only kb in [kb0, wv+4]) ----
    f32x16 o0 = {}, o1 = {};                     // O^T accum, d = 0..31 / 32..63
    float m2 = -3.0e38f, lsum = 0.f;
    const float C = 0.18033688011112042f;        // D^-0.5 * log2(e)

    const int kb0   = (w == 0) ? 4 : 0;          // tiles with all keys < 128 are fully masked pad
    const int kbend = wv + 4;                    // last (partial) causal tile for this wave
    for (int kb = kb0; kb <= kbend; ++kb) {
        // S^T = K·Q^T : A = K-frag direct from global (row = key = l31), B = Q-frag
        f32x16 sacc = {};
        {
            const float* kp = k + ((size_t)bh * TQ + (krow0 + kb * 32 + l31)) * DD + hi * 8;
            #pragma unroll
            for (int s = 0; s < 4; ++s) {
                f32x4 a = *(const f32x4*)(kp + 16 * s);
                f32x4 b = *(const f32x4*)(kp + 16 * s + 4);
                bf16x8 kf;
                #pragma unroll
                for (int e = 0; e < 4; ++e) { kf[e] = (__bf16)a[e]; kf[4 + e] = (__bf16)b[e]; }
                sacc = __builtin_amdgcn_mfma_f32_32x32x16_bf16(kf, qf[s], sacc, 0, 0, 0);
            }
        }
        // mask (only the boundary tile) + online softmax. C/D map (m74-verified):
        // col = query = l31, row = key j = (r&3) + 8*(r>>2) + 4*hi  (+32*kb global)
        float p[16];
        float locmax = -3.0e38f;
        const bool partial = (kb == kbend);      // at kb=wv+4: mask iff j > l31
        #pragma unroll
        for (int r = 0; r < 16; ++r) {
            float sv = sacc[r] * C;
            int j = (r & 3) + 8 * (r >> 2) + 4 * hi;
            if (partial && (j > l31)) sv = -3.0e38f;
            p[r] = sv;
            locmax = fmaxf(locmax, sv);
        }
        locmax = fmaxf(locmax, __shfl_xor(locmax, 32, 64));   // merge hi halves of the key dim
        float mnew = fmaxf(m2, locmax);
        float fac  = exp2f(m2 - mnew);           // first tile: exp2(-huge) = 0
        float ts = 0.f;
        #pragma unroll
        for (int r = 0; r < 16; ++r) { float e = exp2f(p[r] - mnew); p[r] = e; ts += e; }
        ts += __shfl_xor(ts, 32, 64);
        lsum = lsum * fac + ts;
        m2 = mnew;
        #pragma unroll
        for (int r = 0; r < 16; ++r) { o0[r] *= fac; o1[r] *= fac; }

        // ---- P^T C-regs -> B-frags (k-slot j = hi*8 + e + 16s), via pack + shfl_xor(32) ----
        unsigned pk[8], xw[8];
        #pragma unroll
        for (int m = 0; m < 8; ++m) pk[m] = pack2_bf16(p[2 * m], p[2 * m + 1]);
        #pragma unroll
        for (int m = 0; m < 8; ++m) xw[m] = (unsigned)__shfl_xor((int)pk[m], 32, 64);
        u32x4 f0, f1;
        f0[0] = hi ? xw[2] : pk[0]; f0[1] = hi ? xw[3] : pk[1];
        f0[2] = hi ? pk[2] : xw[0]; f0[3] = hi ? pk[3] : xw[1];
        f1[0] = hi ? xw[6] : pk[4]; f1[1] = hi ? xw[7] : pk[5];
        f1[2] = hi ? pk[6] : xw[4]; f1[3] = hi ? pk[7] : xw[5];
        bf16x8 pf0 = __builtin_bit_cast(bf16x8, f0);
        bf16x8 pf1 = __builtin_bit_cast(bf16x8, f1);

        // ---- O^T += V^T · P^T : A = V^T-frag from LDS (row = d, same k-slot map) ----
        const __bf16* vb = &Vt[l31 * PSTRV + kb * 32 + hi * 8];
        bf16x8 v00 = *(const bf16x8*)(vb);
        bf16x8 v01 = *(const bf16x8*)(vb + 16);
        bf16x8 v10 = *(const bf16x8*)(vb + 32 * PSTRV);
        bf16x8 v11 = *(const bf16x8*)(vb + 32 * PSTRV + 16);
        o0 = __builtin_amdgcn_mfma_f32_32x32x16_bf16(v00, pf0, o0, 0, 0, 0);
        o0 = __builtin_amdgcn_mfma_f32_32x32x16_bf16(v01, pf1, o0, 0, 0, 0);
        o1 = __builtin_amdgcn_mfma_f32_32x32x16_bf16(v10, pf0, o1, 0, 0, 0);
        o1 = __builtin_amdgcn_mfma_f32_32x32x16_bf16(v11, pf1, o1, 0, 0, 0);
    }

    // ---- epilogue: O^T -> LDS f32 (stride 132), then coalesced f32x4 stores ----
    float rl = 1.0f / lsum;
    __syncthreads();                             // all waves done reading Vt
    {
        int iq = wv * 32 + l31;
        #pragma unroll
        for (int r = 0; r < 16; ++r) {
            int d = (r & 3) + 8 * (r >> 2) + 4 * hi;
            Ot[d * 132 + iq]        = o0[r] * rl;
            Ot[(d + 32) * 132 + iq] = o1[r] * rl;
        }
    }
    __syncthreads();
    {
        int iq = tid >> 1;                       // 2 threads per query row
        int dh = (tid & 1) * 32;
        float* op = out + base + (size_t)iq * DD + dh;
        #pragma unroll
        for (int u = 0; u < 8; ++u) {
            f32x4 val;
            #pragma unroll
            for (int c = 0; c < 4; ++c) val[c] = Ot[(dh + u * 4 + c) * 132 + iq];
            *(f32x4*)(op + u * 4) = val;
        }
    }
}

extern "C" void kernel_launch(void* const* d_in, const int* in_sizes, int n_in,
                              void* d_out, int out_size, void* d_ws, size_t ws_size,
                              hipStream_t stream) {
    const float* q = (const float*)d_in[0];
    const float* k = (const float*)d_in[1];
    const float* v = (const float*)d_in[2];
    float* out = (float*)d_out;
    dim3 grid(32 * 64);    // (B*H) windows
    dim3 block(256);       // 4 waves, 32 queries each
    lattn_kernel<<<grid, block, 0, stream>>>(q, k, v, out);
}

// Round 5
// 84.162 us; speedup vs baseline: 1.1668x; 1.0695x over previous
//
#include <hip/hip_runtime.h>
#include <hip/hip_bf16.h>

typedef __bf16 bf16x8 __attribute__((ext_vector_type(8)));
typedef float  f32x4  __attribute__((ext_vector_type(4)));
typedef float  f32x16 __attribute__((ext_vector_type(16)));
typedef unsigned int u32x4 __attribute__((ext_vector_type(4)));

#define TQ 8192
#define DD 64
#define PSTRV 264   // Vt row stride (bf16). Rows stay 16B-aligned; block-XOR swizzle spreads banks.

static __device__ __forceinline__ unsigned pack2_bf16(float lo, float hi) {
    unsigned short a = __builtin_bit_cast(unsigned short, (__bf16)lo);
    unsigned short b = __builtin_bit_cast(unsigned short, (__bf16)hi);
    return ((unsigned)b << 16) | (unsigned)a;
}

// Vt[d][j] with 16B-block XOR swizzle: block index (j>>3) ^ ((d>>2)&7).
// - staging writes (fixed j, d=4m+c): banks 16m + 4*((j>>3)^(m&7)) + c -> 8 distinct (was 2)
// - PV b128 reads (row d=l31, 8-elem block): ~2-way (free) instead of 4-way
static __device__ __forceinline__ int vt_idx(int d, int j) {
    return d * PSTRV + ((((j >> 3) ^ ((d >> 2) & 7)) << 3) | (j & 7));
}

__global__ __launch_bounds__(256, 4)
void lattn_kernel(const float* __restrict__ q, const float* __restrict__ k,
                  const float* __restrict__ v, float* __restrict__ out)
{
    // Single LDS buffer: V^T bf16 (swizzled) during the flash loop,
    // reused as f32 [64][132] for the O^T -> coalesced-store transpose.
    __shared__ __align__(16) unsigned char smem[DD * PSTRV * 2];   // 33792 B -> 4 blocks/CU
    __bf16* Vt = (__bf16*)smem;
    float*  Ot = (float*)smem;

    // XCD-aware swizzle (bijective: 2048 = 8*256): blocks on one XCD get
    // consecutive (bh,w) -> window-overlap K/V re-reads hit that XCD's L2.
    const int bx0  = blockIdx.x;
    const int bx   = ((bx0 & 7) << 8) | (bx0 >> 3);
    const int bh   = bx >> 6;        // 0..31
    const int w    = bx & 63;        // window 0..63
    const int tid  = threadIdx.x;    // 0..255
    const int lane = tid & 63;
    const int wv   = tid >> 6;       // wave 0..3, queries wv*32..wv*32+31
    const int l31  = lane & 31;
    const int hi   = lane >> 5;

    const size_t base  = ((size_t)bh * TQ + w * 128) * DD;
    const int    krow0 = w * 128 - 128;          // first key row of the 256-key span

    const int kb0   = (w == 0) ? 4 : 0;          // fully-padded tiles skipped
    const int kbend = wv + 4;                    // last (partial) causal tile

    // ---- prefetch K tile kb0 (hidden under V staging) ----
    const float* kbase = k + ((size_t)bh * TQ + krow0) * DD + hi * 8;
    f32x4 kn[8];
    {
        const float* kp = kbase + (size_t)(kb0 * 32 + l31) * DD;
        #pragma unroll
        for (int s = 0; s < 4; ++s) {
            kn[2 * s]     = *(const f32x4*)(kp + 16 * s);
            kn[2 * s + 1] = *(const f32x4*)(kp + 16 * s + 4);
        }
    }

    // ---- Q B-frags (col = query = wv*32+l31, k-slot d = hi*8 + 16s + e) ----
    bf16x8 qf[4];
    {
        const float* qp = q + base + (size_t)(wv * 32 + l31) * DD + hi * 8;
        #pragma unroll
        for (int s = 0; s < 4; ++s) {
            f32x4 a = *(const f32x4*)(qp + 16 * s);
            f32x4 b = *(const f32x4*)(qp + 16 * s + 4);
            #pragma unroll
            for (int e = 0; e < 4; ++e) { qf[s][e] = (__bf16)a[e]; qf[s][4 + e] = (__bf16)b[e]; }
        }
    }

    // ---- stage V^T (swizzled): Vt[d][j], zero-fill pad rows (w==0) ----
    #pragma unroll
    for (int it = 0; it < 16; ++it) {
        int flat = it * 256 + tid;               // 0..4095 f32x4 chunks
        int j  = flat >> 4;                      // key 0..255
        int d0 = (flat & 15) * 4;
        int gr = krow0 + j;
        f32x4 val = {0.f, 0.f, 0.f, 0.f};
        if (gr >= 0) val = *(const f32x4*)(v + ((size_t)bh * TQ + gr) * DD + d0);
        #pragma unroll
        for (int c = 0; c < 4; ++c) Vt[vt_idx(d0 + c, j)] = (__bf16)val[c];
    }

    // convert prefetched K tile while staging loads drain
    bf16x8 kf[4];
    #pragma unroll
    for (int s = 0; s < 4; ++s) {
        #pragma unroll
        for (int e = 0; e < 4; ++e) { kf[s][e] = (__bf16)kn[2 * s][e]; kf[s][4 + e] = (__bf16)kn[2 * s + 1][e]; }
    }
    __syncthreads();

    // ---- flash loop over 32-key tiles ----
    f32x16 o0 = {}, o1 = {};                     // O^T accum, d = 0..31 / 32..63
    float m2 = -3.0e38f, lsum = 0.f;
    const float C = 0.18033688011112042f;        // D^-0.5 * log2(e)

    for (int kb = kb0; kb <= kbend; ++kb) {
        // issue next tile's K loads NOW; first consumer (cvt) is at loop bottom,
        // so HBM/L2 latency hides under this iteration's MFMA+softmax+PV.
        if (kb < kbend) {
            const float* kp = kbase + (size_t)((kb + 1) * 32 + l31) * DD;
            #pragma unroll
            for (int s = 0; s < 4; ++s) {
                kn[2 * s]     = *(const f32x4*)(kp + 16 * s);
                kn[2 * s + 1] = *(const f32x4*)(kp + 16 * s + 4);
            }
        }

        // S^T = K·Q^T
        f32x16 sacc = {};
        __builtin_amdgcn_s_setprio(1);
        #pragma unroll
        for (int s = 0; s < 4; ++s)
            sacc = __builtin_amdgcn_mfma_f32_32x32x16_bf16(kf[s], qf[s], sacc, 0, 0, 0);
        __builtin_amdgcn_s_setprio(0);

        // mask + online softmax. C/D map: col = query = l31, key j = (r&3)+8*(r>>2)+4*hi
        float p[16];
        float locmax = -3.0e38f;
        const bool partial = (kb == kbend);
        #pragma unroll
        for (int r = 0; r < 16; ++r) {
            float sv = sacc[r] * C;
            int j = (r & 3) + 8 * (r >> 2) + 4 * hi;
            if (partial && (j > l31)) sv = -3.0e38f;
            p[r] = sv;
            locmax = fmaxf(locmax, sv);
        }
        locmax = fmaxf(locmax, __shfl_xor(locmax, 32, 64));
        float mnew = fmaxf(m2, locmax);
        float fac  = exp2f(m2 - mnew);
        float ts = 0.f;
        #pragma unroll
        for (int r = 0; r < 16; ++r) { float e = exp2f(p[r] - mnew); p[r] = e; ts += e; }
        ts += __shfl_xor(ts, 32, 64);
        lsum = lsum * fac + ts;
        m2 = mnew;
        #pragma unroll
        for (int r = 0; r < 16; ++r) { o0[r] *= fac; o1[r] *= fac; }

        // P^T C-regs -> B-frags (k-slot j = hi*8+e+16s) via pack + shfl_xor(32)
        unsigned pk[8], xw[8];
        #pragma unroll
        for (int m = 0; m < 8; ++m) pk[m] = pack2_bf16(p[2 * m], p[2 * m + 1]);
        #pragma unroll
        for (int m = 0; m < 8; ++m) xw[m] = (unsigned)__shfl_xor((int)pk[m], 32, 64);
        u32x4 f0, f1;
        f0[0] = hi ? xw[2] : pk[0]; f0[1] = hi ? xw[3] : pk[1];
        f0[2] = hi ? pk[2] : xw[0]; f0[3] = hi ? pk[3] : xw[1];
        f1[0] = hi ? xw[6] : pk[4]; f1[1] = hi ? xw[7] : pk[5];
        f1[2] = hi ? pk[6] : xw[4]; f1[3] = hi ? pk[7] : xw[5];
        bf16x8 pf0 = __builtin_bit_cast(bf16x8, f0);
        bf16x8 pf1 = __builtin_bit_cast(bf16x8, f1);

        // O^T += V^T · P^T (A = swizzled Vt frags, 16B-aligned b128 reads)
        const int jb = kb * 32 + hi * 8;
        bf16x8 v00 = *(const bf16x8*)&Vt[vt_idx(l31,      jb)];
        bf16x8 v01 = *(const bf16x8*)&Vt[vt_idx(l31,      jb + 16)];
        bf16x8 v10 = *(const bf16x8*)&Vt[vt_idx(l31 + 32, jb)];
        bf16x8 v11 = *(const bf16x8*)&Vt[vt_idx(l31 + 32, jb + 16)];
        __builtin_amdgcn_s_setprio(1);
        o0 = __builtin_amdgcn_mfma_f32_32x32x16_bf16(v00, pf0, o0, 0, 0, 0);
        o0 = __builtin_amdgcn_mfma_f32_32x32x16_bf16(v01, pf1, o0, 0, 0, 0);
        o1 = __builtin_amdgcn_mfma_f32_32x32x16_bf16(v10, pf0, o1, 0, 0, 0);
        o1 = __builtin_amdgcn_mfma_f32_32x32x16_bf16(v11, pf1, o1, 0, 0, 0);
        __builtin_amdgcn_s_setprio(0);

        // consume the prefetch (forces the vmcnt wait HERE, after the compute)
        #pragma unroll
        for (int s = 0; s < 4; ++s) {
            #pragma unroll
            for (int e = 0; e < 4; ++e) { kf[s][e] = (__bf16)kn[2 * s][e]; kf[s][4 + e] = (__bf16)kn[2 * s + 1][e]; }
        }
    }

    // ---- epilogue: O^T -> LDS f32 (stride 132), then coalesced f32x4 stores ----
    float rl = 1.0f / lsum;
    __syncthreads();                             // all waves done reading Vt
    {
        int iq = wv * 32 + l31;
        #pragma unroll
        for (int r = 0; r < 16; ++r) {
            int d = (r & 3) + 8 * (r >> 2) + 4 * hi;
            Ot[d * 132 + iq]        = o0[r] * rl;
            Ot[(d + 32) * 132 + iq] = o1[r] * rl;
        }
    }
    __syncthreads();
    {
        int iq = tid >> 1;                       // 2 threads per query row
        int dh = (tid & 1) * 32;
        float* op = out + base + (size_t)iq * DD + dh;
        #pragma unroll
        for (int u = 0; u < 8; ++u) {
            f32x4 val;
            #pragma unroll
            for (int c = 0; c < 4; ++c) val[c] = Ot[(dh + u * 4 + c) * 132 + iq];
            *(f32x4*)(op + u * 4) = val;
        }
    }
}

extern "C" void kernel_launch(void* const* d_in, const int* in_sizes, int n_in,
                              void* d_out, int out_size, void* d_ws, size_t ws_size,
                              hipStream_t stream) {
    const float* q = (const float*)d_in[0];
    const float* k = (const float*)d_in[1];
    const float* v = (const float*)d_in[2];
    float* out = (float*)d_out;
    dim3 grid(32 * 64);    // (B*H) windows
    dim3 block(256);       // 4 waves, 32 queries each
    lattn_kernel<<<grid, block, 0, stream>>>(q, k, v, out);
}